// Round 12
// baseline (132.222 us; speedup 1.0000x reference)
//
#include <hip/hip_runtime.h>
#include <hip/hip_bf16.h>
#include <hip/hip_fp16.h>

#define IN_F    16384
#define OUT_F   16384
#define CAP     128              // edge slots per row (mean 61, 8.6 sigma margin)
#define NBUCK   512              // coarse buckets: row >> 5, 32 rows each
#define EPB     8192             // edges per partition block (123 chunks)
#define HALF    4096             // per-pass edges (two-pass LDS sort)
#define SLOT    48               // slots per (bucket, chunk); lambda=16, P(ovf)~1e-9
#define TBLK    1024             // transpose blocks inside fused prep kernel

typedef unsigned int u32x4 __attribute__((ext_vector_type(4)));
typedef float f32x4 __attribute__((ext_vector_type(4)));
typedef _Float16 h2 __attribute__((ext_vector_type(2)));

static __device__ __forceinline__ h2 as_h2(unsigned int u) {
    h2 r; __builtin_memcpy(&r, &u, 4); return r;
}

#if defined(__has_builtin)
#if __has_builtin(__builtin_amdgcn_fdot2)
#define HAVE_FDOT2 1
#endif
#endif

// ---------------- fused prep: partition (blocks 0..npart-1) + transpose_x ----
// Partition (R12): EPB=8192 in TWO 4096-edge passes of the proven LDS sort
// (hist -> Hillis scan -> in-LDS re-bin -> address-ordered write-out), with a
// persistent per-bucket base[] so pass-2 runs append after pass-1's. Cell
// payload becomes lambda=16 recs = 128 B = exactly one cache line (R10's
// lambda=8 cells fetched 128 B lines for 64 B used -> 2x HBM amplification in
// accum). Deterministic slots: no global atomics, no memset.
// staging record: x = (row<<14)|col, y = (col<<16)|fp16(val) [accum payload].
// Transpose emits xh as f16 pairs: [2][IN][128] __half (dot2 consumes f16).

__global__ void prep_kernel(const float* __restrict__ x,
                            __half* __restrict__ xTh,
                            const int* __restrict__ rows,
                            const int* __restrict__ cols,
                            const float* __restrict__ vals, int nnz, int npart,
                            uint2* __restrict__ staging,
                            unsigned char* __restrict__ cnt) {
    __shared__ __align__(16) union {
        float tile[64 * 65];               // transpose path (16640 B)
        struct {                           // partition path (~40 KB)
            uint2 recs[HALF];              // 32 KB sorted records (per pass)
            int hist[NBUCK];               // histogram, then local offsets
            int lstart[NBUCK];             // exclusive start within recs
            int base[NBUCK];               // running per-bucket slot base
            int scanbuf[256];              // Hillis scan of pair-sums
        } pa;
    } sm;
    int t = threadIdx.x;
    if ((int)blockIdx.x < npart) {
        // ---- partition EPB edges into 512 buckets, two sorted passes ----
        sm.pa.base[t] = 0; sm.pa.base[t + 256] = 0;
        for (int pass = 0; pass < 2; ++pass) {
            sm.pa.hist[t] = 0; sm.pa.hist[t + 256] = 0;
            __syncthreads();
            int i0 = blockIdx.x * EPB + pass * HALF;
            unsigned int pk[16], vb[16];
#pragma unroll
            for (int k = 0; k < 16; ++k) {
                int i = i0 + k * 256 + t;
                if (i < nnz) {
                    int r = rows[i], c = cols[i];
                    pk[k] = ((unsigned int)r << 14) | (unsigned int)c;
                    vb[k] = ((unsigned int)c << 16) |
                            (unsigned int)__half_as_ushort(__float2half(vals[i]));
                    atomicAdd(&sm.pa.hist[r >> 5], 1);
                } else pk[k] = 0xffffffffu;    // sentinel (valid pk < 2^28)
            }
            __syncthreads();
            // thread t owns bins {2t, 2t+1}; Hillis scan over 256 pair-sums
            int h0 = sm.pa.hist[2 * t], h1 = sm.pa.hist[2 * t + 1];
            sm.pa.scanbuf[t] = h0 + h1;
            __syncthreads();
            for (int off = 1; off < 256; off <<= 1) {
                int add = (t >= off) ? sm.pa.scanbuf[t - off] : 0;
                __syncthreads();
                sm.pa.scanbuf[t] += add;
                __syncthreads();
            }
            int incl = sm.pa.scanbuf[t];
            int excl = incl - (h0 + h1);
            sm.pa.lstart[2 * t]     = excl;
            sm.pa.lstart[2 * t + 1] = excl + h0;
            sm.pa.hist[t] = 0; sm.pa.hist[t + 256] = 0; // reuse: local offsets
            __syncthreads();
#pragma unroll
            for (int k = 0; k < 16; ++k) {
                if (pk[k] != 0xffffffffu) {
                    int b = pk[k] >> 19;               // row >> 5
                    int pos = sm.pa.lstart[b] + atomicAdd(&sm.pa.hist[b], 1);
                    sm.pa.recs[pos] = make_uint2(pk[k], vb[k]);
                }
            }
            __syncthreads();
            int total = sm.pa.scanbuf[255];
            for (int j = t; j < total; j += 256) {
                uint2 rec = sm.pa.recs[j];
                int b = rec.x >> 19;
                int s = sm.pa.base[b] + (j - sm.pa.lstart[b]);
                if (s < SLOT)
                    staging[((size_t)b * npart + blockIdx.x) * SLOT + s] = rec;
            }
            __syncthreads();                 // write-out base reads done
            sm.pa.base[t] += sm.pa.hist[t];  // hist[b] == this pass's count
            sm.pa.base[t + 256] += sm.pa.hist[t + 256];
            __syncthreads();
        }
        // deterministic counts (u8, clamped to SLOT); contiguous u16 store
        unsigned int c0 = (unsigned int)sm.pa.base[2 * t];
        unsigned int c1 = (unsigned int)sm.pa.base[2 * t + 1];
        if (c0 > SLOT) c0 = SLOT;
        if (c1 > SLOT) c1 = SLOT;
        *(unsigned short*)&cnt[(size_t)blockIdx.x * NBUCK + 2 * t] =
            (unsigned short)(c0 | (c1 << 8));
    } else {
        // ---- transpose + f16 quantize: x [256][IN] -> xTh [2][IN][128] ----
        float* tile = (float*)&sm;         // [64][65]
        int bid = blockIdx.x - npart;
        int i0 = (bid & 255) * 64;
        int b0 = (bid >> 8) * 64;
        int tx4 = t & 15;                  // float4 index within 64-col tile
        int r16 = t >> 4;                  // 0..15
#pragma unroll
        for (int k = 0; k < 4; ++k) {
            int row = r16 + k * 16;        // batch row within tile
            f32x4 v = *(const f32x4*)(x + (size_t)(b0 + row) * IN_F + i0 + tx4 * 4);
            tile[row * 65 + tx4 * 4 + 0] = v.x;
            tile[row * 65 + tx4 * 4 + 1] = v.y;
            tile[row * 65 + tx4 * 4 + 2] = v.z;
            tile[row * 65 + tx4 * 4 + 3] = v.w;
        }
        __syncthreads();
        int tx = t & 63, ty = t >> 6;
        int h = b0 >> 7, j0 = b0 & 127;
#pragma unroll
        for (int k = 0; k < 64; k += 4) {
            int col = i0 + ty + k;
            xTh[((size_t)h * IN_F + col) * 128 + j0 + tx] =
                __float2half(tile[tx * 65 + ty + k]);
        }
    }
}

// ---------------- merged scatter + accumulate (h-split) ----------------
// 1024 blocks: bucket = blk>>1 (32 rows), h = blk&1 -> one 4 MB xh half per
// XCD L2. Phase 1: slot-pair-parallel gather (uint4 = 2 recs per thread per
// iteration; staging rows 384 B aligned, pairs at 16 B offsets). Phase 2:
// 8 waves x 4 rows as two sequential row-pairs with per-pair lim; wave-
// uniform edge words -> readfirstlane + SALU decode; f16 pair math with
// v_dot2_f32_f16 (2 edges per dot2). LDS slab epilogue, transposed write.

__global__ void __launch_bounds__(512, 8)
accum_kernel(const unsigned int* __restrict__ xh0,   // [2][IN][64] u32 f16-pairs
             const uint2* __restrict__ staging,      // [NBUCK][npart][SLOT]
             const unsigned char* __restrict__ cnt,  // [npart][NBUCK]
             int npart,
             const float* __restrict__ bias,
             float* __restrict__ out) {              // [256][OUT]
    __shared__ union {
        unsigned int lbin[32 * CAP];                 // 16 KB per-row edge lists
        float slab[32 * 129];                        // 16.5 KB epilogue overlay
    } u;
    __shared__ int lcnt[32];
    __shared__ unsigned char ccnt[256];              // per-chunk counts (<=123)
    int blk = blockIdx.x;
    int h = blk & 1;
    int bu = blk >> 1;
    int o0 = bu * 32;
    int t = threadIdx.x;
    int w = t >> 6, lane = t & 63;
    // zero lbin fully: pad slots decode to (col 0, f16 0) -> contribute 0
    {
        u32x4 z = {0u, 0u, 0u, 0u};
#pragma unroll
        for (int i = 0; i < 2; ++i)
            *(u32x4*)&u.lbin[(t + i * 512) * 4] = z;
    }
    if (t < 32) lcnt[t] = 0;
    if (t < 256) ccnt[t] = (t < npart) ? cnt[(size_t)t * NBUCK + bu] : 0;
    __syncthreads();
    // ---- phase 1: slot-pair-parallel gather into per-row LDS lists ----
    int npairs = npart * (SLOT / 2);                 // 123 * 24 = 2952
    for (int it0 = 0; it0 < npairs; it0 += 512) {
        int item = it0 + t;
        if (item < npairs) {
            int c = item / (SLOT / 2);               // chunk (24 pairs each)
            int s0 = (item - c * (SLOT / 2)) * 2;    // first slot of pair
            int cc2 = (int)ccnt[c];
            if (s0 < cc2) {
                u32x4 rr = *(const u32x4*)(staging +
                               ((size_t)bu * npart + c) * SLOT + s0);
                int rA = (rr.x >> 14) & 31;          // rec0 = (rr.x, rr.y)
                int pA = atomicAdd(&lcnt[rA], 1);    // native ds_add_rtn_u32
                if (pA < CAP) u.lbin[rA * CAP + pA] = rr.y;
                if (s0 + 1 < cc2) {                  // rec1 = (rr.z, rr.w)
                    int rB = (rr.z >> 14) & 31;
                    int pB = atomicAdd(&lcnt[rB], 1);
                    if (pB < CAP) u.lbin[rB * CAP + pB] = rr.w;
                }
            }
        }
    }
    __syncthreads();
    // ---- phase 2: register accumulation, two sequential row-pairs ----
    const unsigned int* xh = xh0 + (size_t)h * IN_F * 64;
    int rl0 = w * 4;
    float aa[4] = {0.f, 0.f, 0.f, 0.f};              // batch 2*lane   per row
    float ab[4] = {0.f, 0.f, 0.f, 0.f};              // batch 2*lane+1 per row
#pragma unroll
    for (int pr = 0; pr < 2; ++pr) {
        int rA = pr * 2, rB = pr * 2 + 1;
        int cA = lcnt[rl0 + rA]; if (cA > CAP) cA = CAP;
        int cB = lcnt[rl0 + rB]; if (cB > CAP) cB = CAP;
        int cm = cA > cB ? cA : cB;
        int lim = (cm + 3) & ~3;
        const u32x4* lbA = (const u32x4*)&u.lbin[(rl0 + rA) * CAP];
        const u32x4* lbB = (const u32x4*)&u.lbin[(rl0 + rB) * CAP];
        if (lim > 0) {
            u32x4 cuA = lbA[0], cuB = lbB[0];
            for (int j = 0; j < lim; j += 4) {
                int jn = (j >> 2) + 1;               // prefetch next group:
                u32x4 nxA = lbA[jn], nxB = lbB[jn];  //  overreads <=16 B land in
                unsigned int e[8] = {cuA.x, cuA.y, cuA.z, cuA.w,   // union slab
                                     cuB.x, cuB.y, cuB.z, cuB.w};  // (safe)
                unsigned int s[8], g[8];
#pragma unroll
                for (int k = 0; k < 8; ++k) {
                    s[k] = __builtin_amdgcn_readfirstlane(e[k]);
                    g[k] = *(xh + ((s[k] >> 16) << 6) + lane);
                }
#pragma unroll
                for (int r = 0; r < 2; ++r) {
                    int ridx = pr * 2 + r;
#pragma unroll
                    for (int pp = 0; pp < 2; ++pp) {
                        int q = r * 4 + pp * 2;
                        // uniform val pair (SALU pack): (v_e0, v_e1) f16x2
                        unsigned int vp = (s[q] & 0xffffu) | (s[q + 1] << 16);
#ifdef HAVE_FDOT2
                        unsigned int pa =
                            __builtin_amdgcn_perm(g[q + 1], g[q], 0x05040100u);
                        unsigned int pb =
                            __builtin_amdgcn_perm(g[q + 1], g[q], 0x07060302u);
                        aa[ridx] = __builtin_amdgcn_fdot2(as_h2(pa), as_h2(vp),
                                                          aa[ridx], false);
                        ab[ridx] = __builtin_amdgcn_fdot2(as_h2(pb), as_h2(vp),
                                                          ab[ridx], false);
#else
                        float v0 = __half2float(__ushort_as_half(
                                       (unsigned short)(vp & 0xffffu)));
                        float v1 = __half2float(__ushort_as_half(
                                       (unsigned short)(vp >> 16)));
                        aa[ridx] = fmaf(__half2float(__ushort_as_half(
                              (unsigned short)(g[q] & 0xffffu))), v0, aa[ridx]);
                        ab[ridx] = fmaf(__half2float(__ushort_as_half(
                              (unsigned short)(g[q] >> 16))), v0, ab[ridx]);
                        aa[ridx] = fmaf(__half2float(__ushort_as_half(
                              (unsigned short)(g[q + 1] & 0xffffu))), v1, aa[ridx]);
                        ab[ridx] = fmaf(__half2float(__ushort_as_half(
                              (unsigned short)(g[q + 1] >> 16))), v1, ab[ridx]);
#endif
                    }
                }
                cuA = nxA; cuB = nxB;
            }
        }
    }
    __syncthreads();                 // all lbin reads done before slab overlay
#pragma unroll
    for (int rr = 0; rr < 4; ++rr) {
        int rl = rl0 + rr;
        u.slab[rl * 129 + 2 * lane + 0] = aa[rr];    // batch 2lane of this half
        u.slab[rl * 129 + 2 * lane + 1] = ab[rr];    // batch 2lane+1
    }
    __syncthreads();
    // ---- epilogue: 1024 items = 128 batches x 8 row-quartets, bias fused ----
#pragma unroll
    for (int it = 0; it < 2; ++it) {
        int item = t + it * 512;
        int bl = item >> 3;              // batch within half, 0..127
        int q = item & 7;                // row quartet, 0..7
        f32x4 bv = *(const f32x4*)(bias + o0 + q * 4);
        f32x4 v;
        v.x = u.slab[(q * 4 + 0) * 129 + bl] + bv.x;
        v.y = u.slab[(q * 4 + 1) * 129 + bl] + bv.y;
        v.z = u.slab[(q * 4 + 2) * 129 + bl] + bv.z;
        v.w = u.slab[(q * 4 + 3) * 129 + bl] + bv.w;
        __builtin_nontemporal_store(v,
            (f32x4*)(out + (size_t)(h * 128 + bl) * OUT_F + o0 + q * 4));
    }
}

extern "C" void kernel_launch(void* const* d_in, const int* in_sizes, int n_in,
                              void* d_out, int out_size, void* d_ws, size_t ws_size,
                              hipStream_t stream) {
    const float* x     = (const float*)d_in[0];
    const float* wvals = (const float*)d_in[1];
    const float* bias  = (const float*)d_in[2];
    const int*   rows  = (const int*)d_in[3];
    const int*   cols  = (const int*)d_in[4];
    float* out = (float*)d_out;
    int nnz = in_sizes[1];

    const size_t MB = 1024 * 1024;
    char* ws = (char*)d_ws;
    __half* xTh = (__half*)(ws);                    // [0, 8 MB): [2][IN][128] f16
    uint2* staging = (uint2*)(ws + 8 * MB);         // [8, ~32.2 MB): [NBUCK][np][SLOT]
    unsigned char* cnt = (unsigned char*)(ws + 34 * MB);  // [np][NBUCK] u8

    int npart = (nnz + EPB - 1) / EPB;              // 123 for nnz = 1e6
    // no memset: every cnt cell is written by prep (deterministic slots)
    prep_kernel<<<npart + TBLK, 256, 0, stream>>>(x, xTh, rows, cols, wvals, nnz,
                                                  npart, staging, cnt);
    accum_kernel<<<NBUCK * 2, 512, 0, stream>>>((const unsigned int*)xTh, staging,
                                                cnt, npart, bias, out);
}

// Round 13
// 124.380 us; speedup vs baseline: 1.0631x; 1.0631x over previous
//
#include <hip/hip_runtime.h>
#include <hip/hip_bf16.h>
#include <hip/hip_fp16.h>

#define IN_F    16384
#define OUT_F   16384
#define CAP     128              // edge slots per row (mean 61, 8.6 sigma margin)
#define NBUCK   512              // coarse buckets: row >> 5, 32 rows each
#define EPB     4096             // edges per partition block (245 chunks)
#define SLOT    32               // slots per (bucket, chunk); lambda=8, P(ovf)~1e-10
#define TBLK    1024             // transpose blocks inside fused prep kernel

typedef unsigned int u32x4 __attribute__((ext_vector_type(4)));
typedef float f32x4 __attribute__((ext_vector_type(4)));
typedef _Float16 h2 __attribute__((ext_vector_type(2)));

static __device__ __forceinline__ h2 as_h2(unsigned int u) {
    h2 r; __builtin_memcpy(&r, &u, 4); return r;
}

#if defined(__has_builtin)
#if __has_builtin(__builtin_amdgcn_fdot2)
#define HAVE_FDOT2 1
#endif
#endif

// ---------------- fused prep: partition (blocks 0..npart-1) + transpose_x ----
// (R11 structure, FROZEN at measured best 125.3 us total. R12's two-pass
// EPB=8192 variant regressed +7 us: partition is barrier/latency-bound, so
// serial passes per block cost more than cache-line fill saves.)
// Partition: LDS sort (hist -> Hillis scan -> in-LDS re-bin) then
// deterministic write-out: bucket b's records of chunk blk go to
// staging[b][blk][0..cnt), cnt[blk][b] = count (u8, every cell written).
// No global atomics, no memset. staging record: x = (row<<14)|col,
// y = (col<<16)|fp16(val) [accum payload]. Transpose emits xh as f16 pairs:
// [2][IN][128] __half (dot2 consumes f16).

__global__ void prep_kernel(const float* __restrict__ x,
                            __half* __restrict__ xTh,
                            const int* __restrict__ rows,
                            const int* __restrict__ cols,
                            const float* __restrict__ vals, int nnz, int npart,
                            uint2* __restrict__ staging,
                            unsigned char* __restrict__ cnt) {
    __shared__ __align__(16) union {
        float tile[64 * 65];               // transpose path (16640 B)
        struct {                           // partition path (~37 KB)
            uint2 recs[EPB];               // 32 KB sorted records
            int hist[NBUCK];               // histogram, then local offsets
            int lstart[NBUCK];             // exclusive start within recs
            int scanbuf[256];              // Hillis scan of pair-sums
        } pa;
    } sm;
    int t = threadIdx.x;
    if ((int)blockIdx.x < npart) {
        // ---- partition EPB edges into 512 buckets, sorted write-out ----
        sm.pa.hist[t] = 0; sm.pa.hist[t + 256] = 0;
        __syncthreads();
        int i0 = blockIdx.x * EPB;
        unsigned int pk[16], vb[16];
#pragma unroll
        for (int k = 0; k < 16; ++k) {
            int i = i0 + k * 256 + t;
            if (i < nnz) {
                int r = rows[i], c = cols[i];
                pk[k] = ((unsigned int)r << 14) | (unsigned int)c;
                vb[k] = ((unsigned int)c << 16) |
                        (unsigned int)__half_as_ushort(__float2half(vals[i]));
                atomicAdd(&sm.pa.hist[r >> 5], 1);
            } else pk[k] = 0xffffffffu;    // sentinel (valid pk < 2^28)
        }
        __syncthreads();
        // each thread owns bins {2t, 2t+1}; Hillis scan over 256 pair-sums
        int h0 = sm.pa.hist[2 * t], h1 = sm.pa.hist[2 * t + 1];
        sm.pa.scanbuf[t] = h0 + h1;
        __syncthreads();
        for (int off = 1; off < 256; off <<= 1) {
            int add = (t >= off) ? sm.pa.scanbuf[t - off] : 0;
            __syncthreads();
            sm.pa.scanbuf[t] += add;
            __syncthreads();
        }
        int incl = sm.pa.scanbuf[t];
        int excl = incl - (h0 + h1);
        sm.pa.lstart[2 * t]     = excl;
        sm.pa.lstart[2 * t + 1] = excl + h0;
        // deterministic counts (u8, clamped to SLOT); contiguous u16 store
        unsigned int c0 = (h0 > SLOT) ? SLOT : h0;
        unsigned int c1 = (h1 > SLOT) ? SLOT : h1;
        *(unsigned short*)&cnt[(size_t)blockIdx.x * NBUCK + 2 * t] =
            (unsigned short)(c0 | (c1 << 8));
        sm.pa.hist[t] = 0; sm.pa.hist[t + 256] = 0;   // reuse as local offsets
        __syncthreads();
#pragma unroll
        for (int k = 0; k < 16; ++k) {
            if (pk[k] != 0xffffffffu) {
                int b = pk[k] >> 19;                   // row >> 5
                int pos = sm.pa.lstart[b] + atomicAdd(&sm.pa.hist[b], 1);
                sm.pa.recs[pos] = make_uint2(pk[k], vb[k]);
            }
        }
        __syncthreads();
        int total = sm.pa.scanbuf[255];
        for (int j = t; j < total; j += 256) {
            uint2 rec = sm.pa.recs[j];
            int b = rec.x >> 19;
            int s = j - sm.pa.lstart[b];
            if (s < SLOT)
                staging[((size_t)b * npart + blockIdx.x) * SLOT + s] = rec;
        }
    } else {
        // ---- transpose + f16 quantize: x [256][IN] -> xTh [2][IN][128] ----
        float* tile = (float*)&sm;         // [64][65]
        int bid = blockIdx.x - npart;
        int i0 = (bid & 255) * 64;
        int b0 = (bid >> 8) * 64;
        int tx4 = t & 15;                  // float4 index within 64-col tile
        int r16 = t >> 4;                  // 0..15
#pragma unroll
        for (int k = 0; k < 4; ++k) {
            int row = r16 + k * 16;        // batch row within tile
            f32x4 v = *(const f32x4*)(x + (size_t)(b0 + row) * IN_F + i0 + tx4 * 4);
            tile[row * 65 + tx4 * 4 + 0] = v.x;
            tile[row * 65 + tx4 * 4 + 1] = v.y;
            tile[row * 65 + tx4 * 4 + 2] = v.z;
            tile[row * 65 + tx4 * 4 + 3] = v.w;
        }
        __syncthreads();
        int tx = t & 63, ty = t >> 6;
        int h = b0 >> 7, j0 = b0 & 127;
#pragma unroll
        for (int k = 0; k < 64; k += 4) {
            int col = i0 + ty + k;
            xTh[((size_t)h * IN_F + col) * 128 + j0 + tx] =
                __float2half(tile[tx * 65 + ty + k]);
        }
    }
}

// ---------------- merged scatter + accumulate (h-split) ----------------
// 1024 blocks: bucket = blk>>1 (32 rows), h = blk&1 -> one 4 MB xh half per
// XCD L2 (merged-halves variant thrashed: FETCH 50-134 MB in R5/R7). Phase 1:
// slot-pair-parallel gather -- each thread covers 2 slots with one uint4 load
// (16 B aligned: SLOT rows are 256 B aligned). Phase 2: 8 waves x 4 rows as
// two sequential row-pairs with per-pair lim (E[max2]~65 < E[max4]~69 of
// Poisson(61)); wave-uniform edge words -> readfirstlane + SALU decode; f16
// pair math with v_dot2_f32_f16 (2 edges per dot2). LDS slab epilogue,
// direct transposed write.

__global__ void __launch_bounds__(512, 8)
accum_kernel(const unsigned int* __restrict__ xh0,   // [2][IN][64] u32 f16-pairs
             const uint2* __restrict__ staging,      // [NBUCK][npart][SLOT]
             const unsigned char* __restrict__ cnt,  // [npart][NBUCK]
             int npart,
             const float* __restrict__ bias,
             float* __restrict__ out) {              // [256][OUT]
    __shared__ union {
        unsigned int lbin[32 * CAP];                 // 16 KB per-row edge lists
        float slab[32 * 129];                        // 16.5 KB epilogue overlay
    } u;
    __shared__ int lcnt[32];
    __shared__ unsigned char ccnt[256];              // per-chunk counts (<=245)
    int blk = blockIdx.x;
    int h = blk & 1;
    int bu = blk >> 1;
    int o0 = bu * 32;
    int t = threadIdx.x;
    int w = t >> 6, lane = t & 63;
    // zero lbin fully: pad slots decode to (col 0, f16 0) -> contribute 0
    {
        u32x4 z = {0u, 0u, 0u, 0u};
#pragma unroll
        for (int i = 0; i < 2; ++i)
            *(u32x4*)&u.lbin[(t + i * 512) * 4] = z;
    }
    if (t < 32) lcnt[t] = 0;
    if (t < 256) ccnt[t] = (t < npart) ? cnt[(size_t)t * NBUCK + bu] : 0;
    __syncthreads();
    // ---- phase 1: slot-pair-parallel gather into per-row LDS lists ----
    int npairs = npart * (SLOT / 2);                 // 3920
    for (int it0 = 0; it0 < npairs; it0 += 512) {
        int item = it0 + t;
        if (item < npairs) {
            int c = item >> 4;                       // chunk (16 pairs each)
            int s0 = (item & 15) * 2;                // first slot of pair
            int cc2 = (int)ccnt[c];
            if (s0 < cc2) {
                u32x4 rr = *(const u32x4*)(staging +
                               ((size_t)bu * npart + c) * SLOT + s0);
                int rA = (rr.x >> 14) & 31;          // rec0 = (rr.x, rr.y)
                int pA = atomicAdd(&lcnt[rA], 1);    // native ds_add_rtn_u32
                if (pA < CAP) u.lbin[rA * CAP + pA] = rr.y;
                if (s0 + 1 < cc2) {                  // rec1 = (rr.z, rr.w)
                    int rB = (rr.z >> 14) & 31;
                    int pB = atomicAdd(&lcnt[rB], 1);
                    if (pB < CAP) u.lbin[rB * CAP + pB] = rr.w;
                }
            }
        }
    }
    __syncthreads();
    // ---- phase 2: register accumulation, two sequential row-pairs ----
    const unsigned int* xh = xh0 + (size_t)h * IN_F * 64;
    int rl0 = w * 4;
    float aa[4] = {0.f, 0.f, 0.f, 0.f};              // batch 2*lane   per row
    float ab[4] = {0.f, 0.f, 0.f, 0.f};              // batch 2*lane+1 per row
#pragma unroll
    for (int pr = 0; pr < 2; ++pr) {
        int rA = pr * 2, rB = pr * 2 + 1;
        int cA = lcnt[rl0 + rA]; if (cA > CAP) cA = CAP;
        int cB = lcnt[rl0 + rB]; if (cB > CAP) cB = CAP;
        int cm = cA > cB ? cA : cB;
        int lim = (cm + 3) & ~3;
        const u32x4* lbA = (const u32x4*)&u.lbin[(rl0 + rA) * CAP];
        const u32x4* lbB = (const u32x4*)&u.lbin[(rl0 + rB) * CAP];
        if (lim > 0) {
            u32x4 cuA = lbA[0], cuB = lbB[0];
            for (int j = 0; j < lim; j += 4) {
                int jn = (j >> 2) + 1;               // prefetch next group:
                u32x4 nxA = lbA[jn], nxB = lbB[jn];  //  overreads <=16 B land in
                unsigned int e[8] = {cuA.x, cuA.y, cuA.z, cuA.w,   // union slab
                                     cuB.x, cuB.y, cuB.z, cuB.w};  // (safe)
                unsigned int s[8], g[8];
#pragma unroll
                for (int k = 0; k < 8; ++k) {
                    s[k] = __builtin_amdgcn_readfirstlane(e[k]);
                    g[k] = *(xh + ((s[k] >> 16) << 6) + lane);
                }
#pragma unroll
                for (int r = 0; r < 2; ++r) {
                    int ridx = pr * 2 + r;
#pragma unroll
                    for (int pp = 0; pp < 2; ++pp) {
                        int q = r * 4 + pp * 2;
                        // uniform val pair (SALU pack): (v_e0, v_e1) f16x2
                        unsigned int vp = (s[q] & 0xffffu) | (s[q + 1] << 16);
#ifdef HAVE_FDOT2
                        unsigned int pa =
                            __builtin_amdgcn_perm(g[q + 1], g[q], 0x05040100u);
                        unsigned int pb =
                            __builtin_amdgcn_perm(g[q + 1], g[q], 0x07060302u);
                        aa[ridx] = __builtin_amdgcn_fdot2(as_h2(pa), as_h2(vp),
                                                          aa[ridx], false);
                        ab[ridx] = __builtin_amdgcn_fdot2(as_h2(pb), as_h2(vp),
                                                          ab[ridx], false);
#else
                        float v0 = __half2float(__ushort_as_half(
                                       (unsigned short)(vp & 0xffffu)));
                        float v1 = __half2float(__ushort_as_half(
                                       (unsigned short)(vp >> 16)));
                        aa[ridx] = fmaf(__half2float(__ushort_as_half(
                              (unsigned short)(g[q] & 0xffffu))), v0, aa[ridx]);
                        ab[ridx] = fmaf(__half2float(__ushort_as_half(
                              (unsigned short)(g[q] >> 16))), v0, ab[ridx]);
                        aa[ridx] = fmaf(__half2float(__ushort_as_half(
                              (unsigned short)(g[q + 1] & 0xffffu))), v1, aa[ridx]);
                        ab[ridx] = fmaf(__half2float(__ushort_as_half(
                              (unsigned short)(g[q + 1] >> 16))), v1, ab[ridx]);
#endif
                    }
                }
                cuA = nxA; cuB = nxB;
            }
        }
    }
    __syncthreads();                 // all lbin reads done before slab overlay
#pragma unroll
    for (int rr = 0; rr < 4; ++rr) {
        int rl = rl0 + rr;
        u.slab[rl * 129 + 2 * lane + 0] = aa[rr];    // batch 2lane of this half
        u.slab[rl * 129 + 2 * lane + 1] = ab[rr];    // batch 2lane+1
    }
    __syncthreads();
    // ---- epilogue: 1024 items = 128 batches x 8 row-quartets, bias fused ----
#pragma unroll
    for (int it = 0; it < 2; ++it) {
        int item = t + it * 512;
        int bl = item >> 3;              // batch within half, 0..127
        int q = item & 7;                // row quartet, 0..7
        f32x4 bv = *(const f32x4*)(bias + o0 + q * 4);
        f32x4 v;
        v.x = u.slab[(q * 4 + 0) * 129 + bl] + bv.x;
        v.y = u.slab[(q * 4 + 1) * 129 + bl] + bv.y;
        v.z = u.slab[(q * 4 + 2) * 129 + bl] + bv.z;
        v.w = u.slab[(q * 4 + 3) * 129 + bl] + bv.w;
        __builtin_nontemporal_store(v,
            (f32x4*)(out + (size_t)(h * 128 + bl) * OUT_F + o0 + q * 4));
    }
}

extern "C" void kernel_launch(void* const* d_in, const int* in_sizes, int n_in,
                              void* d_out, int out_size, void* d_ws, size_t ws_size,
                              hipStream_t stream) {
    const float* x     = (const float*)d_in[0];
    const float* wvals = (const float*)d_in[1];
    const float* bias  = (const float*)d_in[2];
    const int*   rows  = (const int*)d_in[3];
    const int*   cols  = (const int*)d_in[4];
    float* out = (float*)d_out;
    int nnz = in_sizes[1];

    const size_t MB = 1024 * 1024;
    char* ws = (char*)d_ws;
    __half* xTh = (__half*)(ws);                    // [0, 8 MB): [2][IN][128] f16
    uint2* staging = (uint2*)(ws + 8 * MB);         // [8, ~39 MB): [NBUCK][np][SLOT]
    unsigned char* cnt = (unsigned char*)(ws + 40 * MB);  // [np][NBUCK] u8

    int npart = (nnz + EPB - 1) / EPB;              // 245 for nnz = 1e6
    // no memset: every cnt cell is written by prep (deterministic slots)
    prep_kernel<<<npart + TBLK, 256, 0, stream>>>(x, xTh, rows, cols, wvals, nnz,
                                                  npart, staging, cnt);
    accum_kernel<<<NBUCK * 2, 512, 0, stream>>>((const unsigned int*)xTh, staging,
                                                cnt, npart, bias, out);
}